// Round 2
// baseline (1619.972 us; speedup 1.0000x reference)
//
#include <hip/hip_runtime.h>
#include <math.h>

#define B_ROWS 131072
#define TILE   16
#define NTH    256

// LDS layout (float offsets). Padded strides (+4 floats) keep float4 alignment
// and break power-of-2 bank patterns for the LN passes.
#define S_H   516   // stride for [16][512] buffer
#define S_S   260   // stride for [16][256] buffer
#define S_N   132   // stride for [16][128] buffers
#define OFF_H    0      // sH  [16][516] -> 8256 floats ; region reused by c1/c2/e2
#define OFF_C1   0      // [16][132] = 2112
#define OFF_C2   2112
#define OFF_E2   4224
#define OFF_S    8256   // sS  [16][260] -> 4160 ; first 2112 reused by e1 after barrier
#define OFF_E1   8256
#define OFF_X    12416  // [16][8]
#define OFF_HEAD 12544  // [16][4]
#define OFF_RH   12608  // [16][4]
#define OFF_INT  12672  // 32 ints: ord[16], exp[16]
#define SMEM_FLOATS 12704

// Generic dense layer: OUT[r][c] = sum_k IN[r][k]*W[k][c] + bias[c]
// Thread tile: RB rows x CB cols. IN rows are wave-uniform -> LDS broadcast.
template<int K, int N, int RB, int CB, int INS, int OUTS, bool BAR>
__device__ __forceinline__ void dense(const float* __restrict__ W,
                                      const float* __restrict__ bias,
                                      const float* IN, float* OUT, int tid) {
  constexpr int CBLK = N / CB;
  constexpr int RG   = TILE / RB;
  static_assert(CBLK * RG == NTH, "thread mapping mismatch");
  const int cb = tid % CBLK;
  const int rg = tid / CBLK;
  const int c0 = cb * CB;
  const int r0 = rg * RB;
  float acc[RB][CB];
#pragma unroll
  for (int i = 0; i < RB; ++i)
#pragma unroll
    for (int j = 0; j < CB; ++j) acc[i][j] = 0.f;

  for (int k = 0; k < K; k += 4) {
    float4 a[RB];
#pragma unroll
    for (int i = 0; i < RB; ++i)
      a[i] = *(const float4*)(IN + (r0 + i) * INS + k);
#pragma unroll
    for (int kk = 0; kk < 4; ++kk) {
      float w[CB];
      if constexpr (CB == 4) {
        float4 wv = *(const float4*)(W + (k + kk) * N + c0);
        w[0] = wv.x; w[1] = wv.y; w[2] = wv.z; w[3] = wv.w;
      } else if constexpr (CB == 2) {
        float2 wv = *(const float2*)(W + (k + kk) * N + c0);
        w[0] = wv.x; w[1] = wv.y;
      } else {
        w[0] = W[(k + kk) * N + c0];
      }
#pragma unroll
      for (int i = 0; i < RB; ++i) {
        const float av = ((const float*)&a[i])[kk];
#pragma unroll
        for (int j = 0; j < CB; ++j) acc[i][j] += av * w[j];
      }
    }
  }
  if (BAR) __syncthreads();  // needed when OUT aliases IN's region
#pragma unroll
  for (int i = 0; i < RB; ++i)
#pragma unroll
    for (int j = 0; j < CB; ++j)
      OUT[(r0 + i) * OUTS + c0 + j] = acc[i][j] + bias[c0 + j];
}

// Expert dense layer: per-row weight/bias base selected by sExp (rows sorted by
// expert, so 4-row groups are usually uniform -> single weight stream).
template<int K, int N, int RB, int CB, int INS, int OUTS, bool GATHER, bool BAR>
__device__ __forceinline__ void dense_ex(const float* __restrict__ Wb,
                                         const float* __restrict__ Bb,
                                         const int* sOrd, const int* sExp,
                                         const float* IN, float* OUT, int tid) {
  constexpr int CBLK = N / CB;
  constexpr int RG   = TILE / RB;
  static_assert(CBLK * RG == NTH, "thread mapping mismatch");
  const int cb = tid % CBLK;
  const int rg = tid / CBLK;
  const int c0 = cb * CB;
  const int r0 = rg * RB;
  int e[RB], ir[RB];
#pragma unroll
  for (int i = 0; i < RB; ++i) {
    e[i]  = sExp[r0 + i];
    ir[i] = GATHER ? sOrd[r0 + i] : (r0 + i);
  }
  float acc[RB][CB];
#pragma unroll
  for (int i = 0; i < RB; ++i)
#pragma unroll
    for (int j = 0; j < CB; ++j) acc[i][j] = 0.f;

  const bool same = (e[0] == e[RB - 1]);  // rows sorted by expert
  if (same) {
    const float* W = Wb + (size_t)e[0] * K * N;
    for (int k = 0; k < K; k += 4) {
      float4 a[RB];
#pragma unroll
      for (int i = 0; i < RB; ++i)
        a[i] = *(const float4*)(IN + ir[i] * INS + k);
#pragma unroll
      for (int kk = 0; kk < 4; ++kk) {
        float w[CB];
        if constexpr (CB == 2) {
          float2 wv = *(const float2*)(W + (k + kk) * N + c0);
          w[0] = wv.x; w[1] = wv.y;
        } else {
          w[0] = W[(k + kk) * N + c0];
        }
#pragma unroll
        for (int i = 0; i < RB; ++i) {
          const float av = ((const float*)&a[i])[kk];
#pragma unroll
          for (int j = 0; j < CB; ++j) acc[i][j] += av * w[j];
        }
      }
    }
  } else {
    const float* Wp[RB];
#pragma unroll
    for (int i = 0; i < RB; ++i) Wp[i] = Wb + (size_t)e[i] * K * N;
    for (int k = 0; k < K; k += 4) {
      float4 a[RB];
#pragma unroll
      for (int i = 0; i < RB; ++i)
        a[i] = *(const float4*)(IN + ir[i] * INS + k);
#pragma unroll
      for (int kk = 0; kk < 4; ++kk) {
#pragma unroll
        for (int i = 0; i < RB; ++i) {
          float w[CB];
          if constexpr (CB == 2) {
            float2 wv = *(const float2*)(Wp[i] + (k + kk) * N + c0);
            w[0] = wv.x; w[1] = wv.y;
          } else {
            w[0] = Wp[i][(k + kk) * N + c0];
          }
          const float av = ((const float*)&a[i])[kk];
#pragma unroll
          for (int j = 0; j < CB; ++j) acc[i][j] += av * w[j];
        }
      }
    }
  }
  if (BAR) __syncthreads();
#pragma unroll
  for (int i = 0; i < RB; ++i)
#pragma unroll
    for (int j = 0; j < CB; ++j)
      OUT[(r0 + i) * OUTS + c0 + j] = acc[i][j] + Bb[e[i] * N + c0 + j];
}

// Two-pass LayerNorm (+ optional ReLU) in place. 16 threads per row,
// consecutive lanes -> shuffle reduce within aligned 16-lane groups.
template<int N, int S, bool RELU>
__device__ __forceinline__ void ln_rows(float* buf, const float* __restrict__ g,
                                        const float* __restrict__ b, int tid) {
  const int r = tid >> 4, j = tid & 15;
  float* rp = buf + r * S;
  float s = 0.f;
  for (int c = j; c < N; c += 16) s += rp[c];
#pragma unroll
  for (int m = 8; m; m >>= 1) s += __shfl_xor(s, m);
  const float mean = s * (1.f / N);
  float v = 0.f;
  for (int c = j; c < N; c += 16) { const float d = rp[c] - mean; v += d * d; }
#pragma unroll
  for (int m = 8; m; m >>= 1) v += __shfl_xor(v, m);
  const float inv = 1.f / sqrtf(v * (1.f / N) + 1e-5f);
  for (int c = j; c < N; c += 16) {
    const float y = (rp[c] - mean) * inv * g[c] + b[c];
    rp[c] = RELU ? fmaxf(y, 0.f) : y;
  }
}

template<int N, int S>
__device__ __forceinline__ void ln_rows_ex(float* buf, const float* __restrict__ Gb,
                                           const float* __restrict__ Bb,
                                           const int* sExp, int tid) {
  const int r = tid >> 4, j = tid & 15;
  const int e = sExp[r];
  const float* g = Gb + e * N;
  const float* b = Bb + e * N;
  float* rp = buf + r * S;
  float s = 0.f;
  for (int c = j; c < N; c += 16) s += rp[c];
#pragma unroll
  for (int m = 8; m; m >>= 1) s += __shfl_xor(s, m);
  const float mean = s * (1.f / N);
  float v = 0.f;
  for (int c = j; c < N; c += 16) { const float d = rp[c] - mean; v += d * d; }
#pragma unroll
  for (int m = 8; m; m >>= 1) v += __shfl_xor(v, m);
  const float inv = 1.f / sqrtf(v * (1.f / N) + 1e-5f);
  for (int c = j; c < N; c += 16) {
    const float y = (rp[c] - mean) * inv * g[c] + b[c];
    rp[c] = fmaxf(y, 0.f);
  }
}

__global__ void __launch_bounds__(NTH)
moe_fused(const float* __restrict__ x,
          const float* __restrict__ bW1, const float* __restrict__ bb1,
          const float* __restrict__ bg1, const float* __restrict__ bbt1,
          const float* __restrict__ bW2, const float* __restrict__ bb2,
          const float* __restrict__ bg2, const float* __restrict__ bbt2,
          const float* __restrict__ cW1, const float* __restrict__ cb1,
          const float* __restrict__ cg1, const float* __restrict__ cbt1,
          const float* __restrict__ cW2, const float* __restrict__ cb2,
          const float* __restrict__ cg2, const float* __restrict__ cbt2,
          const float* __restrict__ chW, const float* __restrict__ chb,
          const float* __restrict__ rW1, const float* __restrict__ rb1,
          const float* __restrict__ rg1, const float* __restrict__ rbt1,
          const float* __restrict__ rW2, const float* __restrict__ rb2,
          const float* __restrict__ rg2, const float* __restrict__ rbt2,
          const float* __restrict__ rhW, const float* __restrict__ rhb,
          float* __restrict__ out) {
  __shared__ __align__(16) float sm[SMEM_FLOATS];
  const int tid  = threadIdx.x;
  const int row0 = blockIdx.x * TILE;

  float* sH  = sm + OFF_H;
  float* sS  = sm + OFF_S;
  float* sC1 = sm + OFF_C1;
  float* sC2 = sm + OFF_C2;
  float* sE2 = sm + OFF_E2;
  float* sE1 = sm + OFF_E1;
  float* sX  = sm + OFF_X;
  float* sHd = sm + OFF_HEAD;
  float* sRH = sm + OFF_RH;
  int*   sOrd = (int*)(sm + OFF_INT);
  int*   sExp = sOrd + TILE;

  // ---- load x tile [16][5] ----
  if (tid < TILE * 5) {
    const int r = tid / 5, k = tid % 5;
    sX[r * 8 + k] = x[(size_t)(row0 + r) * 5 + k];
  }
  __syncthreads();

  // ---- backbone L1: 5 -> 512, LN, ReLU ----
  for (int o = tid; o < TILE * 512; o += NTH) {
    const int r = o >> 9, c = o & 511;
    float a = 0.f;
#pragma unroll
    for (int k = 0; k < 5; ++k) a += sX[r * 8 + k] * bW1[k * 512 + c];
    sH[r * S_H + c] = a + bb1[c];
  }
  __syncthreads();
  ln_rows<512, S_H, true>(sH, bg1, bbt1, tid);
  __syncthreads();

  // ---- backbone L2: 512 -> 256, LN, ReLU ----
  dense<512, 256, 8, 2, S_H, S_S, false>(bW2, bb2, sH, sS, tid);
  __syncthreads();
  ln_rows<256, S_S, true>(sS, bg2, bbt2, tid);
  __syncthreads();

  // ---- class expert: 256 -> 128 -> 128 ----
  dense<256, 128, 8, 1, S_S, S_N, false>(cW1, cb1, sS, sC1, tid);
  __syncthreads();
  ln_rows<128, S_N, true>(sC1, cg1, cbt1, tid);
  __syncthreads();

  dense<128, 128, 8, 1, S_N, S_N, false>(cW2, cb2, sC1, sC2, tid);
  __syncthreads();
  ln_rows<128, S_N, true>(sC2, cg2, cbt2, tid);
  __syncthreads();

  // ---- class head (also router) ----
  if (tid < TILE * 4) {
    const int r = tid >> 2, n = tid & 3;
    float a = 0.f;
    for (int k = 0; k < 128; ++k) a += sC2[r * S_N + k] * chW[k * 4 + n];
    a += chb[n];
    sHd[r * 4 + n] = a;
    out[(size_t)(row0 + r) * 4 + n] = a;
  }
  __syncthreads();

  // ---- argmax (first-max, matches jnp.argmax) + counting sort by expert ----
  if (tid == 0) {
    int idx[TILE];
    for (int r = 0; r < TILE; ++r) {
      float best = sHd[r * 4]; int bi = 0;
      for (int n = 1; n < 4; ++n) {
        const float vv = sHd[r * 4 + n];
        if (vv > best) { best = vv; bi = n; }
      }
      idx[r] = bi;
    }
    int p = 0;
    for (int e = 0; e < 4; ++e)
      for (int r = 0; r < TILE; ++r)
        if (idx[r] == e) { sOrd[p] = r; sExp[p] = e; ++p; }
  }
  __syncthreads();

  // ---- chosen reg expert: 256 -> 128 -> 128 (rows in expert-sorted order) ----
  // e1 output overlaps dead sS region -> barrier-before-store inside dense_ex
  dense_ex<256, 128, 4, 2, S_S, S_N, true, true>(rW1, rb1, sOrd, sExp, sS, sE1, tid);
  __syncthreads();
  ln_rows_ex<128, S_N>(sE1, rg1, rbt1, sExp, tid);
  __syncthreads();

  dense_ex<128, 128, 4, 2, S_N, S_N, false, false>(rW2, rb2, sOrd, sExp, sE1, sE2, tid);
  __syncthreads();
  ln_rows_ex<128, S_N>(sE2, rg2, rbt2, sExp, tid);
  __syncthreads();

  // ---- reg head + softmax ----
  if (tid < TILE * 3) {
    const int rr = tid / 3, n = tid % 3;
    const int e = sExp[rr];
    float a = 0.f;
    for (int k = 0; k < 128; ++k)
      a += sE2[rr * S_N + k] * rhW[(size_t)(e * 128 + k) * 3 + n];
    a += rhb[e * 3 + n];
    sRH[rr * 4 + n] = a;
  }
  __syncthreads();
  if (tid < TILE) {
    const int rr = tid;
    const float v0 = sRH[rr * 4 + 0];
    const float v1 = sRH[rr * 4 + 1];
    const float v2 = sRH[rr * 4 + 2];
    const float mx = fmaxf(v0, fmaxf(v1, v2));
    const float e0 = expf(v0 - mx), e1 = expf(v1 - mx), e2 = expf(v2 - mx);
    const float inv = 1.f / (e0 + e1 + e2);
    const size_t orow = (size_t)row0 + sOrd[rr];
    float* po = out + (size_t)B_ROWS * 4 + orow * 3;
    po[0] = e0 * inv; po[1] = e1 * inv; po[2] = e2 * inv;
  }
}

extern "C" void kernel_launch(void* const* d_in, const int* in_sizes, int n_in,
                              void* d_out, int out_size, void* d_ws, size_t ws_size,
                              hipStream_t stream) {
  (void)in_sizes; (void)n_in; (void)d_ws; (void)ws_size; (void)out_size;
  const float* p[29];
  for (int i = 0; i < 29; ++i) p[i] = (const float*)d_in[i];
  moe_fused<<<B_ROWS / TILE, NTH, 0, stream>>>(
      p[0],
      p[1], p[2], p[3], p[4],
      p[5], p[6], p[7], p[8],
      p[9], p[10], p[11], p[12],
      p[13], p[14], p[15], p[16],
      p[17], p[18],
      p[19], p[20], p[21], p[22],
      p[23], p[24], p[25], p[26],
      p[27], p[28],
      (float*)d_out);
}

// Round 3
// 965.226 us; speedup vs baseline: 1.6783x; 1.6783x over previous
//
#include <hip/hip_runtime.h>
#include <math.h>

typedef unsigned int u32;
typedef unsigned short u16;
typedef short bf16x8 __attribute__((ext_vector_type(8)));
typedef float f32x4 __attribute__((ext_vector_type(4)));

#define B_ROWS 131072
#define V2_TILE 32
#define NTH 256

// ---------------- LDS arena (dword offsets) ----------------
#define OFF_A    0        // 16896: h fp32 [32][516] -> A1 packed -> e1 packed [4][32][132]
#define OFF_B    16896    // 8448:  s fp32/packed [32][260] -> e2 fp32 experts 0,1
#define OFF_C    25344    // 4224:  c1 [32][132] -> e2 expert 2
#define OFF_D    29568    // 4224:  c2 [32][132] -> e2 expert 3
#define OFF_A0   33792    // 1152:  x packed [32][36] -> chW staged (512 f32)
#define OFF_HD   34944    // 128:   class logits [32][4]
#define OFF_IDX  35072    // 32:    argmax expert per row
#define OFF_RH   35104    // 512:   reg head out [4][32][4]
#define OFF_WSM  35616    // 1548:  rhW (1536 f32) + rhb (12 f32)
#define SMEM_DW  37168

// ---------------- packed-weight layout in d_ws (16B frag units) ----------------
// frag idx within a plane = (ct*KSTEPS + ks)*64 + lane ; hi plane then lo plane.
#define L0H 0        // bW1 zero-padded K=32, N=512: 32ct x 1ks -> 2048 frags/plane
#define L0N 2048
#define L1H 4096     // bW2 K=512 N=256: 16x16 -> 16384
#define L1N 16384
#define L2H 36864    // cW1 K=256 N=128: 8x8 -> 4096
#define L2N 4096
#define L3H 45056    // cW2 K=128 N=128: 8x4 -> 2048
#define L3N 2048
#define L4H 49152    // rW1 concat K=256 N=512: 32x8 -> 16384
#define L4N 16384
#define L5H 81920    // rW2 per-expert K=128 N=128 x4: 32ct x 4ks -> 8192
#define L5N 8192
#define WS_FRAGS 98304
#define WS_NEEDED ((size_t)WS_FRAGS * 16)

#define SEL_HI 0x07060302u
#define SEL_LO 0x05040100u

__device__ __forceinline__ u16 bf16_rne(float f) {
  u32 u = __float_as_uint(f);
  u32 r = u + 0x7fffu + ((u >> 16) & 1u);
  return (u16)(r >> 16);
}
__device__ __forceinline__ u32 pack_split(float v) {
  u16 h = bf16_rne(v);
  float fh = __uint_as_float((u32)h << 16);
  u16 l = bf16_rne(v - fh);
  return ((u32)h << 16) | (u32)l;
}
__device__ __forceinline__ float unpack_hl(u32 d) {
  return __uint_as_float(d & 0xffff0000u) + __uint_as_float(d << 16);
}
__device__ __forceinline__ f32x4 mfma16(bf16x8 a, bf16x8 b, f32x4 c) {
  return __builtin_amdgcn_mfma_f32_16x16x32_bf16(a, b, c, 0, 0, 0);
}

// ---------------- weight pre-pack kernel ----------------
__global__ void __launch_bounds__(NTH) pack_weights(
    const float* __restrict__ bW1, const float* __restrict__ bW2,
    const float* __restrict__ cW1, const float* __restrict__ cW2,
    const float* __restrict__ rW1, const float* __restrict__ rW2,
    uint4* __restrict__ ws) {
  int t = blockIdx.x * NTH + threadIdx.x;  // 0..49151
  int base, nlanes, ksteps, layer;
  if (t < 2048)                { layer = 0; base = L0H; nlanes = L0N; ksteps = 1;  }
  else if (t < 2048+16384)     { layer = 1; base = L1H; nlanes = L1N; ksteps = 16; t -= 2048; }
  else if (t < 2048+16384+4096){ layer = 2; base = L2H; nlanes = L2N; ksteps = 8;  t -= 2048+16384; }
  else if (t < 2048+16384+4096+2048) { layer = 3; base = L3H; nlanes = L3N; ksteps = 4; t -= 2048+16384+4096; }
  else if (t < 2048+16384+4096+2048+16384) { layer = 4; base = L4H; nlanes = L4N; ksteps = 8; t -= 2048+16384+4096+2048; }
  else { layer = 5; base = L5H; nlanes = L5N; ksteps = 4; t -= 2048+16384+4096+2048+16384; }
  const int li = t;
  const int lane = li & 63;
  const int fi = li >> 6;
  const int ct = fi / ksteps;
  const int ks = fi - ct * ksteps;
  const int g = lane >> 4;
  const int col = ct * 16 + (lane & 15);
  const int kb = ks * 32 + 8 * g;
  float w[8];
#pragma unroll
  for (int e = 0; e < 8; ++e) {
    const int k = kb + e;
    float v;
    if (layer == 0)      v = (k < 5) ? bW1[k * 512 + col] : 0.f;
    else if (layer == 1) v = bW2[k * 256 + col];
    else if (layer == 2) v = cW1[k * 128 + col];
    else if (layer == 3) v = cW2[k * 128 + col];
    else if (layer == 4) v = rW1[((col >> 7) * 256 + k) * 128 + (col & 127)];
    else                 v = rW2[((col >> 7) * 128 + k) * 128 + (col & 127)];
    w[e] = v;
  }
  u16 hi[8], lo[8];
#pragma unroll
  for (int e = 0; e < 8; ++e) {
    hi[e] = bf16_rne(w[e]);
    lo[e] = bf16_rne(w[e] - __uint_as_float((u32)hi[e] << 16));
  }
  uint4 H, L;
  H.x = (u32)hi[0] | ((u32)hi[1] << 16); H.y = (u32)hi[2] | ((u32)hi[3] << 16);
  H.z = (u32)hi[4] | ((u32)hi[5] << 16); H.w = (u32)hi[6] | ((u32)hi[7] << 16);
  L.x = (u32)lo[0] | ((u32)lo[1] << 16); L.y = (u32)lo[2] | ((u32)lo[3] << 16);
  L.z = (u32)lo[4] | ((u32)lo[5] << 16); L.w = (u32)lo[6] | ((u32)lo[7] << 16);
  ws[base + li] = H;
  ws[base + nlanes + li] = L;
}

// ---------------- fused main kernel helpers ----------------
// GEMM: A packed(hi|lo) dwords in LDS, W packed frags in global (ws).
// Wave computes 16 rows x (CTS*16) cols. acc += Ahi*Whi + Alo*Whi + Ahi*Wlo.
template<int KSTEPS, int CTS, int ASTR, int OSTR, bool ESPLIT>
__device__ __forceinline__ void gemm_mfma(const u32* sm, int a_base,
                                          const uint4* __restrict__ whi,
                                          const uint4* __restrict__ wlo,
                                          float* smf, int out_base, int row_off,
                                          int n0, const float* __restrict__ bias) {
  const int lane = threadIdx.x & 63;
  const int l15 = lane & 15, g = lane >> 4;
  f32x4 acc[CTS];
#pragma unroll
  for (int c = 0; c < CTS; ++c) acc[c] = (f32x4){0.f, 0.f, 0.f, 0.f};
  const uint4* wh = whi + lane;
  const uint4* wl = wlo + lane;
  const int arow = a_base + l15 * ASTR + 8 * g;
  for (int ks = 0; ks < KSTEPS; ++ks) {
    const uint4* ap = (const uint4*)(sm + arow + ks * 32);
    uint4 dA = ap[0], dB = ap[1];
    uint4 h4, l4;
    h4.x = __builtin_amdgcn_perm(dA.y, dA.x, SEL_HI);
    h4.y = __builtin_amdgcn_perm(dA.w, dA.z, SEL_HI);
    h4.z = __builtin_amdgcn_perm(dB.y, dB.x, SEL_HI);
    h4.w = __builtin_amdgcn_perm(dB.w, dB.z, SEL_HI);
    l4.x = __builtin_amdgcn_perm(dA.y, dA.x, SEL_LO);
    l4.y = __builtin_amdgcn_perm(dA.w, dA.z, SEL_LO);
    l4.z = __builtin_amdgcn_perm(dB.y, dB.x, SEL_LO);
    l4.w = __builtin_amdgcn_perm(dB.w, dB.z, SEL_LO);
    bf16x8 ah = __builtin_bit_cast(bf16x8, h4);
    bf16x8 al = __builtin_bit_cast(bf16x8, l4);
#pragma unroll
    for (int c = 0; c < CTS; ++c) {
      uint4 wH = wh[(c * KSTEPS + ks) * 64];
      uint4 wL = wl[(c * KSTEPS + ks) * 64];
      bf16x8 bh = __builtin_bit_cast(bf16x8, wH);
      bf16x8 bl = __builtin_bit_cast(bf16x8, wL);
      acc[c] = mfma16(ah, bh, acc[c]);
      acc[c] = mfma16(al, bh, acc[c]);
      acc[c] = mfma16(ah, bl, acc[c]);
    }
  }
#pragma unroll
  for (int c = 0; c < CTS; ++c) {
    const int n = n0 + c * 16 + l15;
    int ob = out_base, nc = n;
    if (ESPLIT) { ob = out_base + (n >> 7) * 4224; nc = n & 127; }
    const float bv = bias[n];
#pragma unroll
    for (int i = 0; i < 4; ++i)
      smf[ob + (row_off + 4 * g + i) * OSTR + nc] = acc[c][i] + bv;
  }
}

// LayerNorm + ReLU over one 16-row chunk, data held in registers (read once).
// Reads fp32 from LDS; writes fp32 or packed (hi|lo) in place.
template<int N, bool PACK>
__device__ __forceinline__ void ln_chunk(u32* sm, int base, int stride,
                                         const float* __restrict__ g,
                                         const float* __restrict__ bt) {
  const int t = threadIdx.x;
  const int row = t >> 4, j = t & 15;
  float* rp = (float*)(sm + base + row * stride);
  constexpr int NI = N / 64;
  float4 v[NI];
  float s = 0.f;
#pragma unroll
  for (int i = 0; i < NI; ++i) {
    v[i] = *(const float4*)(rp + 4 * j + 64 * i);
    s += v[i].x + v[i].y + v[i].z + v[i].w;
  }
#pragma unroll
  for (int m = 8; m; m >>= 1) s += __shfl_xor(s, m);
  const float mean = s * (1.f / N);
  float q = 0.f;
#pragma unroll
  for (int i = 0; i < NI; ++i) {
    float dx = v[i].x - mean, dy = v[i].y - mean, dz = v[i].z - mean, dw = v[i].w - mean;
    q += dx * dx + dy * dy + dz * dz + dw * dw;
  }
#pragma unroll
  for (int m = 8; m; m >>= 1) q += __shfl_xor(q, m);
  const float inv = 1.f / sqrtf(q * (1.f / N) + 1e-5f);
#pragma unroll
  for (int i = 0; i < NI; ++i) {
    const int c = 4 * j + 64 * i;
    float4 gv = *(const float4*)(g + c);
    float4 bv = *(const float4*)(bt + c);
    float y0 = fmaxf((v[i].x - mean) * inv * gv.x + bv.x, 0.f);
    float y1 = fmaxf((v[i].y - mean) * inv * gv.y + bv.y, 0.f);
    float y2 = fmaxf((v[i].z - mean) * inv * gv.z + bv.z, 0.f);
    float y3 = fmaxf((v[i].w - mean) * inv * gv.w + bv.w, 0.f);
    if (PACK) {
      u32* rpu = (u32*)rp;
      rpu[c + 0] = pack_split(y0); rpu[c + 1] = pack_split(y1);
      rpu[c + 2] = pack_split(y2); rpu[c + 3] = pack_split(y3);
    } else {
      rp[c + 0] = y0; rp[c + 1] = y1; rp[c + 2] = y2; rp[c + 3] = y3;
    }
  }
}

__device__ __forceinline__ int e2base(int e) {
  return (e < 2) ? (OFF_B + e * 4224) : ((e == 2) ? OFF_C : OFF_D);
}

__global__ void __launch_bounds__(NTH) moe_mfma(
    const float* __restrict__ x,
    const float* __restrict__ bb1, const float* __restrict__ bg1, const float* __restrict__ bbt1,
    const float* __restrict__ bb2, const float* __restrict__ bg2, const float* __restrict__ bbt2,
    const float* __restrict__ cb1, const float* __restrict__ cg1, const float* __restrict__ cbt1,
    const float* __restrict__ cb2, const float* __restrict__ cg2, const float* __restrict__ cbt2,
    const float* __restrict__ chW, const float* __restrict__ chb,
    const float* __restrict__ rb1, const float* __restrict__ rg1, const float* __restrict__ rbt1,
    const float* __restrict__ rb2, const float* __restrict__ rg2, const float* __restrict__ rbt2,
    const float* __restrict__ rhW, const float* __restrict__ rhb,
    float* __restrict__ out, const uint4* __restrict__ wp) {
  __shared__ __align__(16) u32 sm[SMEM_DW];
  float* smf = (float*)sm;
  const int t = threadIdx.x;
  const int wid = t >> 6, wm = wid >> 1, wn = wid & 1;
  const int row0 = blockIdx.x * V2_TILE;

  // stage rhW/rhb
  for (int i = t; i < 1536; i += NTH) smf[OFF_WSM + i] = rhW[i];
  if (t < 12) smf[OFF_WSM + 1536 + t] = rhb[t];

  // pack x -> A0 [32][36] (K zero-padded to 32)
  {
    const int r = t >> 3, k0 = (t & 7) * 4;
#pragma unroll
    for (int i = 0; i < 4; ++i) {
      const int k = k0 + i;
      const float v = (k < 5) ? x[(size_t)(row0 + r) * 5 + k] : 0.f;
      sm[OFF_A0 + r * 36 + k] = pack_split(v);
    }
  }
  __syncthreads();

  // backbone L1: [32][32pad] @ [32][512] -> h fp32 [32][516]
  gemm_mfma<1, 16, 36, 516, false>(sm, OFF_A0 + wm * 16 * 36,
      wp + L0H + (wn * 16) * 64, wp + L0H + L0N + (wn * 16) * 64,
      smf, OFF_A, wm * 16, wn * 256, bb1);
  __syncthreads();
  for (int ch = 0; ch < 2; ++ch) ln_chunk<512, true>(sm, OFF_A + ch * 16 * 516, 516, bg1, bbt1);
  for (int i = t; i < 512; i += NTH) smf[OFF_A0 + i] = chW[i];  // A0 dead -> stage chW
  __syncthreads();

  // backbone L2: K=512 -> s fp32 [32][260]
  gemm_mfma<16, 8, 516, 260, false>(sm, OFF_A + wm * 8256,
      wp + L1H + (wn * 8) * 16 * 64, wp + L1H + L1N + (wn * 8) * 16 * 64,
      smf, OFF_B, wm * 16, wn * 128, bb2);
  __syncthreads();
  for (int ch = 0; ch < 2; ++ch) ln_chunk<256, true>(sm, OFF_B + ch * 16 * 260, 260, bg2, bbt2);
  __syncthreads();

  // class expert L1: K=256 -> c1 [32][132]
  gemm_mfma<8, 4, 260, 132, false>(sm, OFF_B + wm * 16 * 260,
      wp + L2H + (wn * 4) * 8 * 64, wp + L2H + L2N + (wn * 4) * 8 * 64,
      smf, OFF_C, wm * 16, wn * 64, cb1);
  __syncthreads();
  for (int ch = 0; ch < 2; ++ch) ln_chunk<128, true>(sm, OFF_C + ch * 16 * 132, 132, cg1, cbt1);
  __syncthreads();

  // class expert L2: K=128 -> c2 [32][132]
  gemm_mfma<4, 4, 132, 132, false>(sm, OFF_C + wm * 2112,
      wp + L3H + (wn * 4) * 4 * 64, wp + L3H + L3N + (wn * 4) * 4 * 64,
      smf, OFF_D, wm * 16, wn * 64, cb2);
  __syncthreads();
  for (int ch = 0; ch < 2; ++ch) ln_chunk<128, true>(sm, OFF_D + ch * 16 * 132, 132, cg2, cbt2);
  __syncthreads();

  // class head (K=128 packed c2 @ chW[128][4]) + logits out
  {
    const int r = t >> 3, n = (t >> 1) & 3, q = t & 1;
    const uint4* cp = (const uint4*)(sm + OFF_D + r * 132 + q * 64);
    float s = 0.f;
#pragma unroll
    for (int i = 0; i < 16; ++i) {
      uint4 d = cp[i];
      const int kb = q * 64 + 4 * i;
      s += unpack_hl(d.x) * smf[OFF_A0 + (kb + 0) * 4 + n];
      s += unpack_hl(d.y) * smf[OFF_A0 + (kb + 1) * 4 + n];
      s += unpack_hl(d.z) * smf[OFF_A0 + (kb + 2) * 4 + n];
      s += unpack_hl(d.w) * smf[OFF_A0 + (kb + 3) * 4 + n];
    }
    s += __shfl_xor(s, 1);
    if (q == 0) {
      const float v = s + chb[n];
      smf[OFF_HD + r * 4 + n] = v;
      out[(size_t)(row0 + r) * 4 + n] = v;
    }
  }
  __syncthreads();
  if (t < 32) {  // argmax (first max, matches jnp.argmax)
    float best = smf[OFF_HD + t * 4]; int bi = 0;
    for (int n = 1; n < 4; ++n) {
      const float v = smf[OFF_HD + t * 4 + n];
      if (v > best) { best = v; bi = n; }
    }
    sm[OFF_IDX + t] = (u32)bi;
  }

  // reg experts L1 (all 4, concat N=512): K=256, out e1 packed-region split
  gemm_mfma<8, 16, 260, 132, true>(sm, OFF_B + wm * 16 * 260,
      wp + L4H + (wn * 16) * 8 * 64, wp + L4H + L4N + (wn * 16) * 8 * 64,
      smf, OFF_A, wm * 16, wn * 256, rb1);
  __syncthreads();
  for (int c = 0; c < 8; ++c) {
    const int e = c >> 1;
    ln_chunk<128, true>(sm, OFF_A + e * 4224 + (c & 1) * 2112, 132, rg1 + e * 128, rbt1 + e * 128);
  }
  __syncthreads();

  // reg experts L2: per-wave experts {2*wn, 2*wn+1}, K=128
#pragma unroll
  for (int ee = 0; ee < 2; ++ee) {
    const int e = wn * 2 + ee;
    gemm_mfma<4, 8, 132, 132, false>(sm, OFF_A + e * 4224 + wm * 2112,
        wp + L5H + (e * 8) * 4 * 64, wp + L5H + L5N + (e * 8) * 4 * 64,
        smf, e2base(e), wm * 16, 0, rb2 + e * 128);
  }
  __syncthreads();
  for (int c = 0; c < 8; ++c) {
    const int e = c >> 1;
    ln_chunk<128, false>(sm, e2base(e) + (c & 1) * 2112, 132, rg2 + e * 128, rbt2 + e * 128);
  }
  __syncthreads();

  // reg heads (all experts): e2[e] @ rhW[e][128][3]
  {
    const int e = t >> 6, r = (t >> 1) & 31, q = t & 1;
    const float* ep = smf + e2base(e) + r * 132 + q * 64;
    const float* w3 = smf + OFF_WSM + e * 384 + q * 192;
    float s0 = 0.f, s1 = 0.f, s2 = 0.f;
#pragma unroll
    for (int k = 0; k < 64; ++k) {
      const float a = ep[k];
      s0 += a * w3[k * 3 + 0]; s1 += a * w3[k * 3 + 1]; s2 += a * w3[k * 3 + 2];
    }
    s0 += __shfl_xor(s0, 1); s1 += __shfl_xor(s1, 1); s2 += __shfl_xor(s2, 1);
    if (q == 0) {
      smf[OFF_RH + (e * 32 + r) * 4 + 0] = s0 + smf[OFF_WSM + 1536 + e * 3 + 0];
      smf[OFF_RH + (e * 32 + r) * 4 + 1] = s1 + smf[OFF_WSM + 1536 + e * 3 + 1];
      smf[OFF_RH + (e * 32 + r) * 4 + 2] = s2 + smf[OFF_WSM + 1536 + e * 3 + 2];
    }
  }
  __syncthreads();

  // gather chosen expert + softmax
  if (t < 32) {
    const int e = (int)sm[OFF_IDX + t];
    const float v0 = smf[OFF_RH + (e * 32 + t) * 4 + 0];
    const float v1 = smf[OFF_RH + (e * 32 + t) * 4 + 1];
    const float v2 = smf[OFF_RH + (e * 32 + t) * 4 + 2];
    const float mx = fmaxf(v0, fmaxf(v1, v2));
    const float e0 = expf(v0 - mx), e1 = expf(v1 - mx), e2 = expf(v2 - mx);
    const float inv = 1.f / (e0 + e1 + e2);
    float* po = out + (size_t)B_ROWS * 4 + (size_t)(row0 + t) * 3;
    po[0] = e0 * inv; po[1] = e1 * inv; po[2] = e2 * inv;
  }
}

// =================== fallback: round-1 fp32 kernel (used if ws too small) ===================
#define TILE 16
#define S_H 516
#define S_S 260
#define S_N 132
#define F_OFF_H 0
#define F_OFF_C1 0
#define F_OFF_C2 2112
#define F_OFF_E2 4224
#define F_OFF_S 8256
#define F_OFF_E1 8256
#define F_OFF_X 12416
#define F_OFF_HEAD 12544
#define F_OFF_RH 12608
#define F_OFF_INT 12672
#define F_SMEM 12704

template<int K, int N, int RB, int CB, int INS, int OUTS, bool BAR>
__device__ __forceinline__ void dense(const float* __restrict__ W, const float* __restrict__ bias,
                                      const float* IN, float* OUT, int tid) {
  constexpr int CBLK = N / CB;
  const int cb = tid % CBLK, rg = tid / CBLK;
  const int c0 = cb * CB, r0 = rg * RB;
  float acc[RB][CB];
#pragma unroll
  for (int i = 0; i < RB; ++i)
#pragma unroll
    for (int j = 0; j < CB; ++j) acc[i][j] = 0.f;
  for (int k = 0; k < K; k += 4) {
    float4 a[RB];
#pragma unroll
    for (int i = 0; i < RB; ++i) a[i] = *(const float4*)(IN + (r0 + i) * INS + k);
#pragma unroll
    for (int kk = 0; kk < 4; ++kk) {
      float w[CB];
      if constexpr (CB == 2) { float2 wv = *(const float2*)(W + (k + kk) * N + c0); w[0] = wv.x; w[1] = wv.y; }
      else w[0] = W[(k + kk) * N + c0];
#pragma unroll
      for (int i = 0; i < RB; ++i) {
        const float av = ((const float*)&a[i])[kk];
#pragma unroll
        for (int j = 0; j < CB; ++j) acc[i][j] += av * w[j];
      }
    }
  }
  if (BAR) __syncthreads();
#pragma unroll
  for (int i = 0; i < RB; ++i)
#pragma unroll
    for (int j = 0; j < CB; ++j) OUT[(r0 + i) * OUTS + c0 + j] = acc[i][j] + bias[c0 + j];
}

template<int K, int N, int RB, int CB, int INS, int OUTS, bool GATHER, bool BAR>
__device__ __forceinline__ void dense_ex(const float* __restrict__ Wb, const float* __restrict__ Bb,
                                         const int* sOrd, const int* sExp,
                                         const float* IN, float* OUT, int tid) {
  constexpr int CBLK = N / CB;
  const int cb = tid % CBLK, rg = tid / CBLK;
  const int c0 = cb * CB, r0 = rg * RB;
  int e[RB], ir[RB];
#pragma unroll
  for (int i = 0; i < RB; ++i) { e[i] = sExp[r0 + i]; ir[i] = GATHER ? sOrd[r0 + i] : (r0 + i); }
  float acc[RB][CB];
#pragma unroll
  for (int i = 0; i < RB; ++i)
#pragma unroll
    for (int j = 0; j < CB; ++j) acc[i][j] = 0.f;
  const float* Wp[RB];
#pragma unroll
  for (int i = 0; i < RB; ++i) Wp[i] = Wb + (size_t)e[i] * K * N;
  for (int k = 0; k < K; k += 4) {
    float4 a[RB];
#pragma unroll
    for (int i = 0; i < RB; ++i) a[i] = *(const float4*)(IN + ir[i] * INS + k);
#pragma unroll
    for (int kk = 0; kk < 4; ++kk) {
#pragma unroll
      for (int i = 0; i < RB; ++i) {
        float w[CB];
        if constexpr (CB == 2) { float2 wv = *(const float2*)(Wp[i] + (k + kk) * N + c0); w[0] = wv.x; w[1] = wv.y; }
        else w[0] = Wp[i][(k + kk) * N + c0];
        const float av = ((const float*)&a[i])[kk];
#pragma unroll
        for (int j = 0; j < CB; ++j) acc[i][j] += av * w[j];
      }
    }
  }
  if (BAR) __syncthreads();
#pragma unroll
  for (int i = 0; i < RB; ++i)
#pragma unroll
    for (int j = 0; j < CB; ++j) OUT[(r0 + i) * OUTS + c0 + j] = acc[i][j] + Bb[e[i] * N + c0 + j];
}

template<int N, int S, bool RELU>
__device__ __forceinline__ void ln_rows(float* buf, const float* __restrict__ g,
                                        const float* __restrict__ b, int tid) {
  const int r = tid >> 4, j = tid & 15;
  float* rp = buf + r * S;
  float s = 0.f;
  for (int c = j; c < N; c += 16) s += rp[c];
#pragma unroll
  for (int m = 8; m; m >>= 1) s += __shfl_xor(s, m);
  const float mean = s * (1.f / N);
  float v = 0.f;
  for (int c = j; c < N; c += 16) { const float d = rp[c] - mean; v += d * d; }
#pragma unroll
  for (int m = 8; m; m >>= 1) v += __shfl_xor(v, m);
  const float inv = 1.f / sqrtf(v * (1.f / N) + 1e-5f);
  for (int c = j; c < N; c += 16) {
    const float y = (rp[c] - mean) * inv * g[c] + b[c];
    rp[c] = RELU ? fmaxf(y, 0.f) : y;
  }
}

template<int N, int S>
__device__ __forceinline__ void ln_rows_ex(float* buf, const float* __restrict__ Gb,
                                           const float* __restrict__ Bb, const int* sExp, int tid) {
  const int r = tid >> 4, j = tid & 15;
  const int e = sExp[r];
  const float* g = Gb + e * N;
  const float* b = Bb + e * N;
  float* rp = buf + r * S;
  float s = 0.f;
  for (int c = j; c < N; c += 16) s += rp[c];
#pragma unroll
  for (int m = 8; m; m >>= 1) s += __shfl_xor(s, m);
  const float mean = s * (1.f / N);
  float v = 0.f;
  for (int c = j; c < N; c += 16) { const float d = rp[c] - mean; v += d * d; }
#pragma unroll
  for (int m = 8; m; m >>= 1) v += __shfl_xor(v, m);
  const float inv = 1.f / sqrtf(v * (1.f / N) + 1e-5f);
  for (int c = j; c < N; c += 16) {
    const float y = (rp[c] - mean) * inv * g[c] + b[c];
    rp[c] = fmaxf(y, 0.f);
  }
}

__global__ void __launch_bounds__(NTH)
moe_fused(const float* __restrict__ x,
          const float* __restrict__ bW1, const float* __restrict__ bb1,
          const float* __restrict__ bg1, const float* __restrict__ bbt1,
          const float* __restrict__ bW2, const float* __restrict__ bb2,
          const float* __restrict__ bg2, const float* __restrict__ bbt2,
          const float* __restrict__ cW1, const float* __restrict__ cb1,
          const float* __restrict__ cg1, const float* __restrict__ cbt1,
          const float* __restrict__ cW2, const float* __restrict__ cb2,
          const float* __restrict__ cg2, const float* __restrict__ cbt2,
          const float* __restrict__ chW, const float* __restrict__ chb,
          const float* __restrict__ rW1, const float* __restrict__ rb1,
          const float* __restrict__ rg1, const float* __restrict__ rbt1,
          const float* __restrict__ rW2, const float* __restrict__ rb2,
          const float* __restrict__ rg2, const float* __restrict__ rbt2,
          const float* __restrict__ rhW, const float* __restrict__ rhb,
          float* __restrict__ out) {
  __shared__ __align__(16) float smf[F_SMEM];
  const int tid = threadIdx.x;
  const int row0 = blockIdx.x * TILE;
  float* sH = smf + F_OFF_H;
  float* sS = smf + F_OFF_S;
  float* sC1 = smf + F_OFF_C1;
  float* sC2 = smf + F_OFF_C2;
  float* sE2 = smf + F_OFF_E2;
  float* sE1 = smf + F_OFF_E1;
  float* sX = smf + F_OFF_X;
  float* sHd = smf + F_OFF_HEAD;
  float* sRH = smf + F_OFF_RH;
  int* sOrd = (int*)(smf + F_OFF_INT);
  int* sExp = sOrd + TILE;

  if (tid < TILE * 5) {
    const int r = tid / 5, k = tid % 5;
    sX[r * 8 + k] = x[(size_t)(row0 + r) * 5 + k];
  }
  __syncthreads();
  for (int o = tid; o < TILE * 512; o += NTH) {
    const int r = o >> 9, c = o & 511;
    float a = 0.f;
#pragma unroll
    for (int k = 0; k < 5; ++k) a += sX[r * 8 + k] * bW1[k * 512 + c];
    sH[r * S_H + c] = a + bb1[c];
  }
  __syncthreads();
  ln_rows<512, S_H, true>(sH, bg1, bbt1, tid);
  __syncthreads();
  dense<512, 256, 8, 2, S_H, S_S, false>(bW2, bb2, sH, sS, tid);
  __syncthreads();
  ln_rows<256, S_S, true>(sS, bg2, bbt2, tid);
  __syncthreads();
  dense<256, 128, 8, 1, S_S, S_N, false>(cW1, cb1, sS, sC1, tid);
  __syncthreads();
  ln_rows<128, S_N, true>(sC1, cg1, cbt1, tid);
  __syncthreads();
  dense<128, 128, 8, 1, S_N, S_N, false>(cW2, cb2, sC1, sC2, tid);
  __syncthreads();
  ln_rows<128, S_N, true>(sC2, cg2, cbt2, tid);
  __syncthreads();
  if (tid < TILE * 4) {
    const int r = tid >> 2, n = tid & 3;
    float a = 0.f;
    for (int k = 0; k < 128; ++k) a += sC2[r * S_N + k] * chW[k * 4 + n];
    a += chb[n];
    sHd[r * 4 + n] = a;
    out[(size_t)(row0 + r) * 4 + n] = a;
  }
  __syncthreads();
  if (tid == 0) {
    int idx[TILE];
    for (int r = 0; r < TILE; ++r) {
      float best = sHd[r * 4]; int bi = 0;
      for (int n = 1; n < 4; ++n) {
        const float vv = sHd[r * 4 + n];
        if (vv > best) { best = vv; bi = n; }
      }
      idx[r] = bi;
    }
    int p = 0;
    for (int e = 0; e < 4; ++e)
      for (int r = 0; r < TILE; ++r)
        if (idx[r] == e) { sOrd[p] = r; sExp[p] = e; ++p; }
  }
  __syncthreads();
  dense_ex<256, 128, 4, 2, S_S, S_N, true, true>(rW1, rb1, sOrd, sExp, sS, sE1, tid);
  __syncthreads();
  ln_rows_ex<128, S_N>(sE1, rg1, rbt1, sExp, tid);
  __syncthreads();
  dense_ex<128, 128, 4, 2, S_N, S_N, false, false>(rW2, rb2, sOrd, sExp, sE1, sE2, tid);
  __syncthreads();
  ln_rows_ex<128, S_N>(sE2, rg2, rbt2, sExp, tid);
  __syncthreads();
  if (tid < TILE * 3) {
    const int rr = tid / 3, n = tid % 3;
    const int e = sExp[rr];
    float a = 0.f;
    for (int k = 0; k < 128; ++k) a += sE2[rr * S_N + k] * rhW[(size_t)(e * 128 + k) * 3 + n];
    a += rhb[e * 3 + n];
    sRH[rr * 4 + n] = a;
  }
  __syncthreads();
  if (tid < TILE) {
    const int rr = tid;
    const float v0 = sRH[rr * 4 + 0];
    const float v1 = sRH[rr * 4 + 1];
    const float v2 = sRH[rr * 4 + 2];
    const float mx = fmaxf(v0, fmaxf(v1, v2));
    const float e0 = expf(v0 - mx), e1 = expf(v1 - mx), e2 = expf(v2 - mx);
    const float inv = 1.f / (e0 + e1 + e2);
    const size_t orow = (size_t)row0 + sOrd[rr];
    float* po = out + (size_t)B_ROWS * 4 + orow * 3;
    po[0] = e0 * inv; po[1] = e1 * inv; po[2] = e2 * inv;
  }
}

extern "C" void kernel_launch(void* const* d_in, const int* in_sizes, int n_in,
                              void* d_out, int out_size, void* d_ws, size_t ws_size,
                              hipStream_t stream) {
  (void)in_sizes; (void)n_in; (void)out_size;
  const float* p[29];
  for (int i = 0; i < 29; ++i) p[i] = (const float*)d_in[i];
  if (ws_size >= WS_NEEDED) {
    pack_weights<<<192, NTH, 0, stream>>>(p[1], p[5], p[9], p[13], p[19], p[23], (uint4*)d_ws);
    moe_mfma<<<B_ROWS / V2_TILE, NTH, 0, stream>>>(
        p[0],
        p[2], p[3], p[4],
        p[6], p[7], p[8],
        p[10], p[11], p[12],
        p[14], p[15], p[16],
        p[17], p[18],
        p[20], p[21], p[22],
        p[24], p[25], p[26],
        p[27], p[28],
        (float*)d_out, (const uint4*)d_ws);
  } else {
    moe_fused<<<B_ROWS / TILE, NTH, 0, stream>>>(
        p[0], p[1], p[2], p[3], p[4], p[5], p[6], p[7], p[8],
        p[9], p[10], p[11], p[12], p[13], p[14], p[15], p[16],
        p[17], p[18], p[19], p[20], p[21], p[22], p[23], p[24],
        p[25], p[26], p[27], p[28],
        (float*)d_out);
  }
}

// Round 4
// 503.900 us; speedup vs baseline: 3.2149x; 1.9155x over previous
//
#include <hip/hip_runtime.h>
#include <math.h>

typedef unsigned int u32;
typedef unsigned short u16;
typedef short bf16x8 __attribute__((ext_vector_type(8)));
typedef float f32x4 __attribute__((ext_vector_type(4)));

#define B_ROWS 131072
#define R_TILE 64
#define NTH 512

// ---------------- packed-weight layout in d_ws (16B frag units) ----------------
#define L0H 0        // bW1 K=32(pad) N=512: ct=32, ks=1 -> 2048 frags/plane
#define L0N 2048
#define L1H 4096     // bW2 K=512 N=256: ct=16, ks=16 -> 16384
#define L1N 16384
#define L2H 36864    // cW1 K=256 N=128: ct=8, ks=8 -> 4096
#define L2N 4096
#define L3H 45056    // cW2 K=128 N=128: ct=8, ks=4 -> 2048
#define L3N 2048
#define L4H 49152    // rW1 concat K=256 N=512: ct=32, ks=8 -> 16384
#define L4N 16384
#define L5H 81920    // rW2 concat K=128 N=512: ct=32, ks=4 -> 8192
#define L5N 8192
#define WS_FRAGS 98304
#define WS_NEEDED ((size_t)WS_FRAGS * 16 + 128)   // + LN-stats constants (27 floats)

// ---------------- LDS arena (dword offsets), main kernel ----------------
#define A_X      0      // x packed [64][36] = 2304   (dead after phase1; inside E region)
#define A_CHUNK  2304   // h-chunk packed [64][132] = 8448 ; later c2 packed
#define A_S      10752  // s packed [64][260] = 16640
#define A_C1     27392  // c1 packed [64][132] = 8448  (ends 35840)
#define A_E      0      // e1/e2 packed concat [64][532] = 34048 (expert col off e*132)
#define A_WP     35840  // wave partials [8][64][2] = 1024
#define A_RS     36864  // row stats [4][64][2] = 512 (e=0 for shared layers; also hstats)
#define A_LG     37376  // class logits [64][4] = 256
#define A_IDX    37632  // argmax [64]
#define A_RH     37696  // reg head out [4][64][4] = 1024
#define SMEM_DW  38720  // 154880 B

#define SEL_HI 0x07060302u
#define SEL_LO 0x05040100u

__device__ __forceinline__ u16 bf16_rne(float f) {
  u32 u = __float_as_uint(f);
  u32 r = u + 0x7fffu + ((u >> 16) & 1u);
  return (u16)(r >> 16);
}
__device__ __forceinline__ u32 pack_split(float v) {
  u16 h = bf16_rne(v);
  float fh = __uint_as_float((u32)h << 16);
  u16 l = bf16_rne(v - fh);
  return ((u32)h << 16) | (u32)l;
}
__device__ __forceinline__ float unpack_hl(u32 d) {
  return __uint_as_float(d & 0xffff0000u) + __uint_as_float(d << 16);
}
__device__ __forceinline__ f32x4 mfma16(bf16x8 a, bf16x8 b, f32x4 c) {
  return __builtin_amdgcn_mfma_f32_16x16x32_bf16(a, b, c, 0, 0, 0);
}

// ---------------- weight pre-pack kernel (frag layout, hi/lo planes) ----------------
__global__ void __launch_bounds__(256) pack_weights(
    const float* __restrict__ bW1, const float* __restrict__ bW2,
    const float* __restrict__ cW1, const float* __restrict__ cW2,
    const float* __restrict__ rW1, const float* __restrict__ rW2,
    uint4* __restrict__ ws) {
  int t = blockIdx.x * 256 + threadIdx.x;  // 0..49151
  int base, nlanes, ksteps, layer;
  if (t < 2048)                { layer = 0; base = L0H; nlanes = L0N; ksteps = 1;  }
  else if (t < 2048+16384)     { layer = 1; base = L1H; nlanes = L1N; ksteps = 16; t -= 2048; }
  else if (t < 2048+16384+4096){ layer = 2; base = L2H; nlanes = L2N; ksteps = 8;  t -= 2048+16384; }
  else if (t < 2048+16384+4096+2048) { layer = 3; base = L3H; nlanes = L3N; ksteps = 4; t -= 2048+16384+4096; }
  else if (t < 2048+16384+4096+2048+16384) { layer = 4; base = L4H; nlanes = L4N; ksteps = 8; t -= 2048+16384+4096+2048; }
  else { layer = 5; base = L5H; nlanes = L5N; ksteps = 4; t -= 2048+16384+4096+2048+16384; }
  const int li = t;
  const int lane = li & 63;
  const int fi = li >> 6;
  const int ct = fi / ksteps;
  const int ks = fi - ct * ksteps;
  const int g = lane >> 4;
  const int col = ct * 16 + (lane & 15);
  const int kb = ks * 32 + 8 * g;
  float w[8];
#pragma unroll
  for (int e = 0; e < 8; ++e) {
    const int k = kb + e;
    float v;
    if (layer == 0)      v = (k < 5) ? bW1[k * 512 + col] : 0.f;
    else if (layer == 1) v = bW2[k * 256 + col];
    else if (layer == 2) v = cW1[k * 128 + col];
    else if (layer == 3) v = cW2[k * 128 + col];
    else if (layer == 4) v = rW1[((col >> 7) * 256 + k) * 128 + (col & 127)];
    else                 v = rW2[((col >> 7) * 128 + k) * 128 + (col & 127)];
    w[e] = v;
  }
  u16 hi[8], lo[8];
#pragma unroll
  for (int e = 0; e < 8; ++e) {
    hi[e] = bf16_rne(w[e]);
    lo[e] = bf16_rne(w[e] - __uint_as_float((u32)hi[e] << 16));
  }
  uint4 H, L;
  H.x = (u32)hi[0] | ((u32)hi[1] << 16); H.y = (u32)hi[2] | ((u32)hi[3] << 16);
  H.z = (u32)hi[4] | ((u32)hi[5] << 16); H.w = (u32)hi[6] | ((u32)hi[7] << 16);
  L.x = (u32)lo[0] | ((u32)lo[1] << 16); L.y = (u32)lo[2] | ((u32)lo[3] << 16);
  L.z = (u32)lo[4] | ((u32)lo[5] << 16); L.w = (u32)lo[6] | ((u32)lo[7] << 16);
  ws[base + li] = H;
  ws[base + nlanes + li] = L;
}

// ---------------- LN(h) closed-form constants ----------------
// mean_r = cs[5] + sum_k x_rk*cs[k]
// E[h^2]_r = cs[26] + sum_k x_rk*cs[21+k] + sum_{k>=k2} cs[6+p]*x_rk*x_rk2 (off-diag pre-doubled)
__global__ void __launch_bounds__(256) pack_stats(const float* __restrict__ bW1,
                                                  const float* __restrict__ bb1,
                                                  float* __restrict__ wsf) {
  __shared__ float red[27 * 256];
  const int t = threadIdx.x;
  float part[27];
#pragma unroll
  for (int j = 0; j < 27; ++j) part[j] = 0.f;
  for (int c = t; c < 512; c += 256) {
    float wv[5];
#pragma unroll
    for (int k = 0; k < 5; ++k) wv[k] = bW1[k * 512 + c];
    const float bc = bb1[c];
#pragma unroll
    for (int k = 0; k < 5; ++k) part[k] += wv[k];
    part[5] += bc;
    int p = 0;
#pragma unroll
    for (int k = 0; k < 5; ++k)
#pragma unroll
      for (int k2 = 0; k2 <= k; ++k2) part[6 + p++] += wv[k] * wv[k2];
#pragma unroll
    for (int k = 0; k < 5; ++k) part[21 + k] += wv[k] * bc;
    part[26] += bc * bc;
  }
#pragma unroll
  for (int j = 0; j < 27; ++j) red[j * 256 + t] = part[j];
  __syncthreads();
  if (t < 27) {
    float s = 0.f;
    for (int i = 0; i < 256; ++i) s += red[t * 256 + i];
    s *= (1.f / 512.f);
    if (t >= 6 && t < 21) {
      const int p = t - 6;
      const bool diag = (p == 0 || p == 2 || p == 5 || p == 9 || p == 14);
      if (!diag) s *= 2.f;
    }
    if (t >= 21 && t < 26) s *= 2.f;
    wsf[t] = s;
  }
}

// ---------------- main kernel building blocks ----------------
// GEMM: A packed(hi|lo) u32 in LDS (lane l15 = batch row within rowgroup),
// W frags from global. acc[rg][ct] += Ahi*Whi + Alo*Whi + Ahi*Wlo.
template<int KSTEPS, int CTS, int RGS, int LKS>
__device__ __forceinline__ void gemm_rg(const u32* sm, int a_base, int a_stride,
                                        const uint4* __restrict__ wh,
                                        const uint4* __restrict__ wl,
                                        f32x4 (&acc)[RGS][CTS]) {
  const int lane = threadIdx.x & 63;
  const int l15 = lane & 15, g = lane >> 4;
  for (int ks = 0; ks < KSTEPS; ++ks) {
    bf16x8 ah[RGS], al[RGS];
#pragma unroll
    for (int rg = 0; rg < RGS; ++rg) {
      const uint4* ap = (const uint4*)(sm + a_base + (rg * 16 + l15) * a_stride + ks * 32 + 8 * g);
      uint4 dA = ap[0], dB = ap[1];
      uint4 h4, l4;
      h4.x = __builtin_amdgcn_perm(dA.y, dA.x, SEL_HI);
      h4.y = __builtin_amdgcn_perm(dA.w, dA.z, SEL_HI);
      h4.z = __builtin_amdgcn_perm(dB.y, dB.x, SEL_HI);
      h4.w = __builtin_amdgcn_perm(dB.w, dB.z, SEL_HI);
      l4.x = __builtin_amdgcn_perm(dA.y, dA.x, SEL_LO);
      l4.y = __builtin_amdgcn_perm(dA.w, dA.z, SEL_LO);
      l4.z = __builtin_amdgcn_perm(dB.y, dB.x, SEL_LO);
      l4.w = __builtin_amdgcn_perm(dB.w, dB.z, SEL_LO);
      ah[rg] = __builtin_bit_cast(bf16x8, h4);
      al[rg] = __builtin_bit_cast(bf16x8, l4);
    }
#pragma unroll
    for (int c = 0; c < CTS; ++c) {
      uint4 wH = wh[(c * LKS + ks) * 64];
      uint4 wL = wl[(c * LKS + ks) * 64];
      bf16x8 bh = __builtin_bit_cast(bf16x8, wH);
      bf16x8 bl = __builtin_bit_cast(bf16x8, wL);
#pragma unroll
      for (int rg = 0; rg < RGS; ++rg) {
        acc[rg][c] = mfma16(ah[rg], bh, acc[rg][c]);
        acc[rg][c] = mfma16(al[rg], bh, acc[rg][c]);
        acc[rg][c] = mfma16(ah[rg], bl, acc[rg][c]);
      }
    }
  }
}

template<int RGS, int CTS>
__device__ __forceinline__ void add_bias(f32x4 (&acc)[RGS][CTS],
                                         const float* __restrict__ bias, int col0) {
  const int l15 = threadIdx.x & 15;
#pragma unroll
  for (int c = 0; c < CTS; ++c) {
    const float bv = bias[col0 + c * 16 + l15];
#pragma unroll
    for (int rg = 0; rg < RGS; ++rg)
#pragma unroll
      for (int i = 0; i < 4; ++i) acc[rg][c][i] += bv;
  }
}

// per-wave LN stats partials -> A_WP[w][row][2]  (acc row = rg*16 + 4g + i)
template<int RGS, int CTS>
__device__ __forceinline__ void stats_partial(const f32x4 (&acc)[RGS][CTS], float* smf, int w) {
  const int lane = threadIdx.x & 63;
  const int l15 = lane & 15, g = lane >> 4;
  float s1[RGS][4], s2[RGS][4];
#pragma unroll
  for (int rg = 0; rg < RGS; ++rg)
#pragma unroll
    for (int i = 0; i < 4; ++i) {
      float a = 0.f, b = 0.f;
#pragma unroll
      for (int c = 0; c < CTS; ++c) { const float v = acc[rg][c][i]; a += v; b += v * v; }
      s1[rg][i] = a; s2[rg][i] = b;
    }
#pragma unroll
  for (int m = 1; m <= 8; m <<= 1)
#pragma unroll
    for (int rg = 0; rg < RGS; ++rg)
#pragma unroll
      for (int i = 0; i < 4; ++i) {
        s1[rg][i] += __shfl_xor(s1[rg][i], m);
        s2[rg][i] += __shfl_xor(s2[rg][i], m);
      }
  if (l15 == 0) {
#pragma unroll
    for (int rg = 0; rg < RGS; ++rg)
#pragma unroll
      for (int i = 0; i < 4; ++i) {
        const int row = rg * 16 + 4 * g + i;
        smf[A_WP + (w * 64 + row) * 2]     = s1[rg][i];
        smf[A_WP + (w * 64 + row) * 2 + 1] = s2[rg][i];
      }
  }
}

// combine all 8 waves (shared layers) -> A_RS[0]
template<int N>
__device__ __forceinline__ void combine_shared(float* smf, int t) {
  if (t < 64) {
    float a = 0.f, b = 0.f;
#pragma unroll
    for (int w = 0; w < 8; ++w) {
      a += smf[A_WP + (w * 64 + t) * 2];
      b += smf[A_WP + (w * 64 + t) * 2 + 1];
    }
    const float mean = a * (1.f / N);
    const float var = b * (1.f / N) - mean * mean;
    smf[A_RS + t * 2]     = mean;
    smf[A_RS + t * 2 + 1] = rsqrtf(fmaxf(var, 0.f) + 1e-5f);
  }
}

// combine wave pairs (expert layers, N=128) -> A_RS[e]
__device__ __forceinline__ void combine_expert(float* smf, int t) {
  if (t < 256) {
    const int e = t >> 6, r = t & 63;
    const float a = smf[A_WP + ((2 * e) * 64 + r) * 2]     + smf[A_WP + ((2 * e + 1) * 64 + r) * 2];
    const float b = smf[A_WP + ((2 * e) * 64 + r) * 2 + 1] + smf[A_WP + ((2 * e + 1) * 64 + r) * 2 + 1];
    const float mean = a * (1.f / 128.f);
    const float var = b * (1.f / 128.f) - mean * mean;
    smf[A_RS + e * 128 + r * 2]     = mean;
    smf[A_RS + e * 128 + r * 2 + 1] = rsqrtf(fmaxf(var, 0.f) + 1e-5f);
  }
}

// normalize acc with stats at st_ofs, scale/shift, ReLU, pack hi|lo, store to LDS
template<int RGS, int CTS>
__device__ __forceinline__ void norm_pack_store(const f32x4 (&acc)[RGS][CTS], u32* sm,
    int st_ofs, const float* __restrict__ gamma, const float* __restrict__ beta,
    int col0, int dst, int dstr, int dcol0) {
  float* smf = (float*)sm;
  const int lane = threadIdx.x & 63;
  const int l15 = lane & 15, g = lane >> 4;
  float gv[CTS], bv[CTS];
#pragma unroll
  for (int c = 0; c < CTS; ++c) {
    gv[c] = gamma[col0 + c * 16 + l15];
    bv[c] = beta[col0 + c * 16 + l15];
  }
#pragma unroll
  for (int rg = 0; rg < RGS; ++rg)
#pragma unroll
    for (int i = 0; i < 4; ++i) {
      const int row = rg * 16 + 4 * g + i;
      const float mean = smf[st_ofs + row * 2];
      const float inv  = smf[st_ofs + row * 2 + 1];
#pragma unroll
      for (int c = 0; c < CTS; ++c) {
        float y = (acc[rg][c][i] - mean) * inv * gv[c] + bv[c];
        y = fmaxf(y, 0.f);
        sm[dst + row * dstr + dcol0 + c * 16 + l15] = pack_split(y);
      }
    }
}

__global__ void __launch_bounds__(NTH, 1) moe_v3(
    const float* __restrict__ x,
    const float* __restrict__ bb1, const float* __restrict__ bg1, const float* __restrict__ bbt1,
    const float* __restrict__ bb2, const float* __restrict__ bg2, const float* __restrict__ bbt2,
    const float* __restrict__ cb1, const float* __restrict__ cg1, const float* __restrict__ cbt1,
    const float* __restrict__ cb2, const float* __restrict__ cg2, const float* __restrict__ cbt2,
    const float* __restrict__ chW, const float* __restrict__ chb,
    const float* __restrict__ rb1, const float* __restrict__ rg1, const float* __restrict__ rbt1,
    const float* __restrict__ rb2, const float* __restrict__ rg2, const float* __restrict__ rbt2,
    const float* __restrict__ rhW, const float* __restrict__ rhb,
    float* __restrict__ out, const uint4* __restrict__ wp, const float* __restrict__ cs) {
  __shared__ __align__(16) u32 sm[SMEM_DW];
  float* smf = (float*)sm;
  const int t = threadIdx.x;
  const int w = t >> 6;
  const int row0 = blockIdx.x * R_TILE;

  // ---- stage x packed [64][36] (K zero-padded to 32) ----
  {
    const int r = t >> 3, k0 = (t & 7) * 4;
#pragma unroll
    for (int i = 0; i < 4; ++i) {
      const int k = k0 + i;
      const float v = (k < 5) ? x[(size_t)(row0 + r) * 5 + k] : 0.f;
      sm[A_X + r * 36 + k] = pack_split(v);
    }
  }
  // ---- closed-form LN(h) stats per row -> A_RS[0] ----
  if (t < 64) {
    float xv[5];
#pragma unroll
    for (int k = 0; k < 5; ++k) xv[k] = x[(size_t)(row0 + t) * 5 + k];
    float mean = cs[5];
#pragma unroll
    for (int k = 0; k < 5; ++k) mean += xv[k] * cs[k];
    float e2 = cs[26];
    int p = 0;
#pragma unroll
    for (int k = 0; k < 5; ++k) {
      e2 += xv[k] * cs[21 + k];
#pragma unroll
      for (int k2 = 0; k2 <= k; ++k2) e2 += cs[6 + p++] * xv[k] * xv[k2];
    }
    const float var = e2 - mean * mean;
    smf[A_RS + t * 2]     = mean;
    smf[A_RS + t * 2 + 1] = rsqrtf(fmaxf(var, 0.f) + 1e-5f);
  }
  __syncthreads();

  // ---- phase 1: fused L1 -> LN -> pack -> partial L2, h in 128-col chunks ----
  f32x4 accS[4][2];
#pragma unroll
  for (int rg = 0; rg < 4; ++rg)
#pragma unroll
    for (int c = 0; c < 2; ++c) accS[rg][c] = (f32x4){0.f, 0.f, 0.f, 0.f};
  for (int kc = 0; kc < 4; ++kc) {
    f32x4 acc1[4][1];
#pragma unroll
    for (int rg = 0; rg < 4; ++rg) acc1[rg][0] = (f32x4){0.f, 0.f, 0.f, 0.f};
    gemm_rg<1, 1, 4, 1>(sm, A_X, 36,
        wp + L0H + (kc * 8 + w) * 64 + (t & 63),
        wp + L0H + L0N + (kc * 8 + w) * 64 + (t & 63), acc1);
    add_bias<4, 1>(acc1, bb1, kc * 128 + w * 16);
    norm_pack_store<4, 1>(acc1, sm, A_RS, bg1, bbt1, kc * 128 + w * 16, A_CHUNK, 132, w * 16);
    __syncthreads();
    gemm_rg<4, 2, 4, 16>(sm, A_CHUNK, 132,
        wp + L1H + (w * 32 + kc * 4) * 64 + (t & 63),
        wp + L1H + L1N + (w * 32 + kc * 4) * 64 + (t & 63), accS);
    __syncthreads();
  }

  // ---- s: bias + in-reg LN + pack -> A_S ----
  add_bias<4, 2>(accS, bb2, w * 32);
  stats_partial<4, 2>(accS, smf, w);
  __syncthreads();
  combine_shared<256>(smf, t);
  __syncthreads();
  norm_pack_store<4, 2>(accS, sm, A_RS, bg2, bbt2, w * 32, A_S, 260, w * 32);
  __syncthreads();

  // ---- class expert L1: K=256 -> c1 ----
  {
    f32x4 accC[4][1];
#pragma unroll
    for (int rg = 0; rg < 4; ++rg) accC[rg][0] = (f32x4){0.f, 0.f, 0.f, 0.f};
    gemm_rg<8, 1, 4, 8>(sm, A_S, 260,
        wp + L2H + (w * 8) * 64 + (t & 63),
        wp + L2H + L2N + (w * 8) * 64 + (t & 63), accC);
    add_bias<4, 1>(accC, cb1, w * 16);
    stats_partial<4, 1>(accC, smf, w);
    __syncthreads();
    combine_shared<128>(smf, t);
    __syncthreads();
    norm_pack_store<4, 1>(accC, sm, A_RS, cg1, cbt1, w * 16, A_C1, 132, w * 16);
    __syncthreads();
  }

  // ---- class expert L2: K=128 -> c2 (into chunk buf) ----
  {
    f32x4 accD[4][1];
#pragma unroll
    for (int rg = 0; rg < 4; ++rg) accD[rg][0] = (f32x4){0.f, 0.f, 0.f, 0.f};
    gemm_rg<4, 1, 4, 4>(sm, A_C1, 132,
        wp + L3H + (w * 4) * 64 + (t & 63),
        wp + L3H + L3N + (w * 4) * 64 + (t & 63), accD);
    add_bias<4, 1>(accD, cb2, w * 16);
    stats_partial<4, 1>(accD, smf, w);
    __syncthreads();
    combine_shared<128>(smf, t);
    __syncthreads();
    norm_pack_store<4, 1>(accD, sm, A_RS, cg2, cbt2, w * 16, A_CHUNK, 132, w * 16);
    __syncthreads();
  }

  // ---- class head + logits out ----
  {
    const int r = t >> 3, o = (t >> 1) & 3, q = t & 1;
    const uint4* cp = (const uint4*)(sm + A_CHUNK + r * 132 + q * 64);
    float s = 0.f;
#pragma unroll
    for (int i = 0; i < 16; ++i) {
      uint4 d = cp[i];
      const int kb = q * 64 + 4 * i;
      s += unpack_hl(d.x) * chW[(kb + 0) * 4 + o];
      s += unpack_hl(d.y) * chW[(kb + 1) * 4 + o];
      s += unpack_hl(d.z) * chW[(kb + 2) * 4 + o];
      s += unpack_hl(d.w) * chW[(kb + 3) * 4 + o];
    }
    s += __shfl_xor(s, 1);
    if (q == 0) {
      const float v = s + chb[o];
      smf[A_LG + r * 4 + o] = v;
      out[(size_t)(row0 + r) * 4 + o] = v;
    }
  }
  __syncthreads();
  if (t < 64) {  // argmax (first max, matches jnp.argmax)
    float best = smf[A_LG + t * 4];
    int bi = 0;
#pragma unroll
    for (int n = 1; n < 4; ++n) {
      const float v = smf[A_LG + t * 4 + n];
      if (v > best) { best = v; bi = n; }
    }
    sm[A_IDX + t] = (u32)bi;
  }

  // ---- reg experts L1 (concat N=512): K=256 from s ----
  {
    f32x4 accE[4][4];
#pragma unroll
    for (int rg = 0; rg < 4; ++rg)
#pragma unroll
      for (int c = 0; c < 4; ++c) accE[rg][c] = (f32x4){0.f, 0.f, 0.f, 0.f};
    gemm_rg<8, 4, 4, 8>(sm, A_S, 260,
        wp + L4H + (w * 32) * 64 + (t & 63),
        wp + L4H + L4N + (w * 32) * 64 + (t & 63), accE);
    add_bias<4, 4>(accE, rb1, w * 64);      // rb1 flat [E*128] == concat col
    stats_partial<4, 4>(accE, smf, w);
    __syncthreads();                        // also: all waves done reading s / head done
    combine_expert(smf, t);
    __syncthreads();
    norm_pack_store<4, 4>(accE, sm, A_RS + (w >> 1) * 128, rg1, rbt1, w * 64,
                          A_E, 532, (w >> 1) * 132 + (w & 1) * 64);
    __syncthreads();
  }

  // ---- reg experts L2 (concat): K=128 from e1 ----
  {
    f32x4 accF[4][4];
#pragma unroll
    for (int rg = 0; rg < 4; ++rg)
#pragma unroll
      for (int c = 0; c < 4; ++c) accF[rg][c] = (f32x4){0.f, 0.f, 0.f, 0.f};
    gemm_rg<4, 4, 4, 4>(sm, A_E + (w >> 1) * 132, 532,
        wp + L5H + (w * 16) * 64 + (t & 63),
        wp + L5H + L5N + (w * 16) * 64 + (t & 63), accF);
    add_bias<4, 4>(accF, rb2, w * 64);
    stats_partial<4, 4>(accF, smf, w);
    __syncthreads();                        // all waves done reading e1
    combine_expert(smf, t);
    __syncthreads();
    norm_pack_store<4, 4>(accF, sm, A_RS + (w >> 1) * 128, rg2, rbt2, w * 64,
                          A_E, 532, (w >> 1) * 132 + (w & 1) * 64);
    __syncthreads();
  }

  // ---- reg heads (all experts): e2[e] @ rhW[e][128][3] ----
  for (int u = t; u < 768; u += NTH) {
    const int r = u & 63, rest = u >> 6;    // rest 0..11 = e*3+o
    const int e = rest / 3, o = rest - 3 * e;
    float s = rhb[e * 3 + o];
    const u32* ep = sm + A_E + r * 532 + e * 132;
    for (int k = 0; k < 128; ++k)
      s += unpack_hl(ep[k]) * rhW[(e * 128 + k) * 3 + o];
    smf[A_RH + e * 256 + r * 4 + o] = s;
  }
  __syncthreads();

  // ---- gather chosen expert + softmax ----
  if (t < 64) {
    const int e = (int)sm[A_IDX + t];
    const float v0 = smf[A_RH + e * 256 + t * 4 + 0];
    const float v1 = smf[A_RH + e * 256 + t * 4 + 1];
    const float v2 = smf[A_RH + e * 256 + t * 4 + 2];
    const float mx = fmaxf(v0, fmaxf(v1, v2));
    const float e0 = expf(v0 - mx), e1 = expf(v1 - mx), e2 = expf(v2 - mx);
    const float inv = 1.f / (e0 + e1 + e2);
    float* po = out + (size_t)B_ROWS * 4 + (size_t)(row0 + t) * 3;
    po[0] = e0 * inv; po[1] = e1 * inv; po[2] = e2 * inv;
  }
}

// =================== fallback: round-1 fp32 kernel (used if ws too small) ===================
#define TILE 16
#define S_H 516
#define S_S 260
#define S_N 132
#define F_OFF_H 0
#define F_OFF_C1 0
#define F_OFF_C2 2112
#define F_OFF_E2 4224
#define F_OFF_S 8256
#define F_OFF_E1 8256
#define F_OFF_X 12416
#define F_OFF_HEAD 12544
#define F_OFF_RH 12608
#define F_OFF_INT 12672
#define F_SMEM 12704

template<int K, int N, int RB, int CB, int INS, int OUTS, bool BAR>
__device__ __forceinline__ void dense(const float* __restrict__ W, const float* __restrict__ bias,
                                      const float* IN, float* OUT, int tid) {
  constexpr int CBLK = N / CB;
  const int cb = tid % CBLK, rg = tid / CBLK;
  const int c0 = cb * CB, r0 = rg * RB;
  float acc[RB][CB];
#pragma unroll
  for (int i = 0; i < RB; ++i)
#pragma unroll
    for (int j = 0; j < CB; ++j) acc[i][j] = 0.f;
  for (int k = 0; k < K; k += 4) {
    float4 a[RB];
#pragma unroll
    for (int i = 0; i < RB; ++i) a[i] = *(const float4*)(IN + (r0 + i) * INS + k);
#pragma unroll
    for (int kk = 0; kk < 4; ++kk) {
      float wv2[CB];
      if constexpr (CB == 2) { float2 wv = *(const float2*)(W + (k + kk) * N + c0); wv2[0] = wv.x; wv2[1] = wv.y; }
      else wv2[0] = W[(k + kk) * N + c0];
#pragma unroll
      for (int i = 0; i < RB; ++i) {
        const float av = ((const float*)&a[i])[kk];
#pragma unroll
        for (int j = 0; j < CB; ++j) acc[i][j] += av * wv2[j];
      }
    }
  }
  if (BAR) __syncthreads();
#pragma unroll
  for (int i = 0; i < RB; ++i)
#pragma unroll
    for (int j = 0; j < CB; ++j) OUT[(r0 + i) * OUTS + c0 + j] = acc[i][j] + bias[c0 + j];
}

template<int K, int N, int RB, int CB, int INS, int OUTS, bool GATHER, bool BAR>
__device__ __forceinline__ void dense_ex(const float* __restrict__ Wb, const float* __restrict__ Bb,
                                         const int* sOrd, const int* sExp,
                                         const float* IN, float* OUT, int tid) {
  constexpr int CBLK = N / CB;
  const int cb = tid % CBLK, rg = tid / CBLK;
  const int c0 = cb * CB, r0 = rg * RB;
  int e[RB], ir[RB];
#pragma unroll
  for (int i = 0; i < RB; ++i) { e[i] = sExp[r0 + i]; ir[i] = GATHER ? sOrd[r0 + i] : (r0 + i); }
  float acc[RB][CB];
#pragma unroll
  for (int i = 0; i < RB; ++i)
#pragma unroll
    for (int j = 0; j < CB; ++j) acc[i][j] = 0.f;
  const float* Wp[RB];
#pragma unroll
  for (int i = 0; i < RB; ++i) Wp[i] = Wb + (size_t)e[i] * K * N;
  for (int k = 0; k < K; k += 4) {
    float4 a[RB];
#pragma unroll
    for (int i = 0; i < RB; ++i) a[i] = *(const float4*)(IN + ir[i] * INS + k);
#pragma unroll
    for (int kk = 0; kk < 4; ++kk) {
#pragma unroll
      for (int i = 0; i < RB; ++i) {
        float wv2[CB];
        if constexpr (CB == 2) { float2 wv = *(const float2*)(Wp[i] + (k + kk) * N + c0); wv2[0] = wv.x; wv2[1] = wv.y; }
        else wv2[0] = Wp[i][(k + kk) * N + c0];
        const float av = ((const float*)&a[i])[kk];
#pragma unroll
        for (int j = 0; j < CB; ++j) acc[i][j] += av * wv2[j];
      }
    }
  }
  if (BAR) __syncthreads();
#pragma unroll
  for (int i = 0; i < RB; ++i)
#pragma unroll
    for (int j = 0; j < CB; ++j) OUT[(r0 + i) * OUTS + c0 + j] = acc[i][j] + Bb[e[i] * N + c0 + j];
}

template<int N, int S, bool RELU>
__device__ __forceinline__ void ln_rows(float* buf, const float* __restrict__ g,
                                        const float* __restrict__ b, int tid) {
  const int r = tid >> 4, j = tid & 15;
  float* rp = buf + r * S;
  float s = 0.f;
  for (int c = j; c < N; c += 16) s += rp[c];
#pragma unroll
  for (int m = 8; m; m >>= 1) s += __shfl_xor(s, m);
  const float mean = s * (1.f / N);
  float v = 0.f;
  for (int c = j; c < N; c += 16) { const float d = rp[c] - mean; v += d * d; }
#pragma unroll
  for (int m = 8; m; m >>= 1) v += __shfl_xor(v, m);
  const float inv = 1.f / sqrtf(v * (1.f / N) + 1e-5f);
  for (int c = j; c < N; c += 16) {
    const float y = (rp[c] - mean) * inv * g[c] + b[c];
    rp[c] = RELU ? fmaxf(y, 0.f) : y;
  }
}

template<int N, int S>
__device__ __forceinline__ void ln_rows_ex(float* buf, const float* __restrict__ Gb,
                                           const float* __restrict__ Bb, const int* sExp, int tid) {
  const int r = tid >> 4, j = tid & 15;
  const int e = sExp[r];
  const float* g = Gb + e * N;
  const float* b = Bb + e * N;
  float* rp = buf + r * S;
  float s = 0.f;
  for (int c = j; c < N; c += 16) s += rp[c];
#pragma unroll
  for (int m = 8; m; m >>= 1) s += __shfl_xor(s, m);
  const float mean = s * (1.f / N);
  float v = 0.f;
  for (int c = j; c < N; c += 16) { const float d = rp[c] - mean; v += d * d; }
#pragma unroll
  for (int m = 8; m; m >>= 1) v += __shfl_xor(v, m);
  const float inv = 1.f / sqrtf(v * (1.f / N) + 1e-5f);
  for (int c = j; c < N; c += 16) {
    const float y = (rp[c] - mean) * inv * g[c] + b[c];
    rp[c] = fmaxf(y, 0.f);
  }
}

__global__ void __launch_bounds__(256)
moe_fused(const float* __restrict__ x,
          const float* __restrict__ bW1, const float* __restrict__ bb1,
          const float* __restrict__ bg1, const float* __restrict__ bbt1,
          const float* __restrict__ bW2, const float* __restrict__ bb2,
          const float* __restrict__ bg2, const float* __restrict__ bbt2,
          const float* __restrict__ cW1, const float* __restrict__ cb1,
          const float* __restrict__ cg1, const float* __restrict__ cbt1,
          const float* __restrict__ cW2, const float* __restrict__ cb2,
          const float* __restrict__ cg2, const float* __restrict__ cbt2,
          const float* __restrict__ chW, const float* __restrict__ chb,
          const float* __restrict__ rW1, const float* __restrict__ rb1,
          const float* __restrict__ rg1, const float* __restrict__ rbt1,
          const float* __restrict__ rW2, const float* __restrict__ rb2,
          const float* __restrict__ rg2, const float* __restrict__ rbt2,
          const float* __restrict__ rhW, const float* __restrict__ rhb,
          float* __restrict__ out) {
  __shared__ __align__(16) float smf[F_SMEM];
  const int tid = threadIdx.x;
  const int row0 = blockIdx.x * TILE;
  float* sH = smf + F_OFF_H;
  float* sS = smf + F_OFF_S;
  float* sC1 = smf + F_OFF_C1;
  float* sC2 = smf + F_OFF_C2;
  float* sE2 = smf + F_OFF_E2;
  float* sE1 = smf + F_OFF_E1;
  float* sX = smf + F_OFF_X;
  float* sHd = smf + F_OFF_HEAD;
  float* sRH = smf + F_OFF_RH;
  int* sOrd = (int*)(smf + F_OFF_INT);
  int* sExp = sOrd + TILE;

  if (tid < TILE * 5) {
    const int r = tid / 5, k = tid % 5;
    sX[r * 8 + k] = x[(size_t)(row0 + r) * 5 + k];
  }
  __syncthreads();
  for (int o = tid; o < TILE * 512; o += 256) {
    const int r = o >> 9, c = o & 511;
    float a = 0.f;
#pragma unroll
    for (int k = 0; k < 5; ++k) a += sX[r * 8 + k] * bW1[k * 512 + c];
    sH[r * S_H + c] = a + bb1[c];
  }
  __syncthreads();
  ln_rows<512, S_H, true>(sH, bg1, bbt1, tid);
  __syncthreads();
  dense<512, 256, 8, 2, S_H, S_S, false>(bW2, bb2, sH, sS, tid);
  __syncthreads();
  ln_rows<256, S_S, true>(sS, bg2, bbt2, tid);
  __syncthreads();
  dense<256, 128, 8, 1, S_S, S_N, false>(cW1, cb1, sS, sC1, tid);
  __syncthreads();
  ln_rows<128, S_N, true>(sC1, cg1, cbt1, tid);
  __syncthreads();
  dense<128, 128, 8, 1, S_N, S_N, false>(cW2, cb2, sC1, sC2, tid);
  __syncthreads();
  ln_rows<128, S_N, true>(sC2, cg2, cbt2, tid);
  __syncthreads();
  if (tid < TILE * 4) {
    const int r = tid >> 2, n = tid & 3;
    float a = 0.f;
    for (int k = 0; k < 128; ++k) a += sC2[r * S_N + k] * chW[k * 4 + n];
    a += chb[n];
    sHd[r * 4 + n] = a;
    out[(size_t)(row0 + r) * 4 + n] = a;
  }
  __syncthreads();
  if (tid == 0) {
    int idx[TILE];
    for (int r = 0; r < TILE; ++r) {
      float best = sHd[r * 4]; int bi = 0;
      for (int n = 1; n < 4; ++n) {
        const float vv = sHd[r * 4 + n];
        if (vv > best) { best = vv; bi = n; }
      }
      idx[r] = bi;
    }
    int p = 0;
    for (int e = 0; e < 4; ++e)
      for (int r = 0; r < TILE; ++r)
        if (idx[r] == e) { sOrd[p] = r; sExp[p] = e; ++p; }
  }
  __syncthreads();
  dense_ex<256, 128, 4, 2, S_S, S_N, true, true>(rW1, rb1, sOrd, sExp, sS, sE1, tid);
  __syncthreads();
  ln_rows_ex<128, S_N>(sE1, rg1, rbt1, sExp, tid);
  __syncthreads();
  dense_ex<128, 128, 4, 2, S_N, S_N, false, false>(rW2, rb2, sOrd, sExp, sE1, sE2, tid);
  __syncthreads();
  ln_rows_ex<128, S_N>(sE2, rg2, rbt2, sExp, tid);
  __syncthreads();
  if (tid < TILE * 3) {
    const int rr = tid / 3, n = tid % 3;
    const int e = sExp[rr];
    float a = 0.f;
    for (int k = 0; k < 128; ++k) a += sE2[rr * S_N + k] * rhW[(size_t)(e * 128 + k) * 3 + n];
    a += rhb[e * 3 + n];
    sRH[rr * 4 + n] = a;
  }
  __syncthreads();
  if (tid < TILE) {
    const int rr = tid;
    const float v0 = sRH[rr * 4 + 0];
    const float v1 = sRH[rr * 4 + 1];
    const float v2 = sRH[rr * 4 + 2];
    const float mx = fmaxf(v0, fmaxf(v1, v2));
    const float e0 = expf(v0 - mx), e1 = expf(v1 - mx), e2 = expf(v2 - mx);
    const float inv = 1.f / (e0 + e1 + e2);
    const size_t orow = (size_t)row0 + sOrd[rr];
    float* po = out + (size_t)B_ROWS * 4 + orow * 3;
    po[0] = e0 * inv; po[1] = e1 * inv; po[2] = e2 * inv;
  }
}

extern "C" void kernel_launch(void* const* d_in, const int* in_sizes, int n_in,
                              void* d_out, int out_size, void* d_ws, size_t ws_size,
                              hipStream_t stream) {
  (void)in_sizes; (void)n_in; (void)out_size;
  const float* p[29];
  for (int i = 0; i < 29; ++i) p[i] = (const float*)d_in[i];
  if (ws_size >= WS_NEEDED) {
    float* wsf = (float*)((char*)d_ws + (size_t)WS_FRAGS * 16);
    pack_weights<<<192, 256, 0, stream>>>(p[1], p[5], p[9], p[13], p[19], p[23], (uint4*)d_ws);
    pack_stats<<<1, 256, 0, stream>>>(p[1], p[2], wsf);
    moe_v3<<<B_ROWS / R_TILE, NTH, 0, stream>>>(
        p[0],
        p[2], p[3], p[4],
        p[6], p[7], p[8],
        p[10], p[11], p[12],
        p[14], p[15], p[16],
        p[17], p[18],
        p[20], p[21], p[22],
        p[24], p[25], p[26],
        p[27], p[28],
        (float*)d_out, (const uint4*)d_ws, wsf);
  } else {
    moe_fused<<<B_ROWS / TILE, 256, 0, stream>>>(
        p[0], p[1], p[2], p[3], p[4], p[5], p[6], p[7], p[8],
        p[9], p[10], p[11], p[12], p[13], p[14], p[15], p[16],
        p[17], p[18], p[19], p[20], p[21], p[22], p[23], p[24],
        p[25], p[26], p[27], p[28],
        (float*)d_out);
  }
}